// Round 1
// baseline (467.084 us; speedup 1.0000x reference)
//
#include <hip/hip_runtime.h>
#include <stdint.h>

typedef unsigned short u16;
typedef __attribute__((ext_vector_type(8))) short bf16x8;
typedef __attribute__((ext_vector_type(4))) float f32x4;

__device__ __forceinline__ u16 f2b(float f) {
  uint32_t x = __builtin_bit_cast(uint32_t, f);
  uint32_t r = (x + 0x7FFFu + ((x >> 16) & 1u)) >> 16;
  return (u16)r;
}
__device__ __forceinline__ float b2f(u16 u) {
  return __builtin_bit_cast(float, ((uint32_t)u) << 16);
}

// ---------------------------------------------------------------- cvt f32->bf16
__global__ __launch_bounds__(256) void cvt_bf16(const float* __restrict__ in,
                                                u16* __restrict__ out, int n) {
  int i = (blockIdx.x * 256 + threadIdx.x) * 4;
  if (i + 3 < n) {
    float4 f = *(const float4*)(in + i);
    ushort4 u;
    u.x = f2b(f.x); u.y = f2b(f.y); u.z = f2b(f.z); u.w = f2b(f.w);
    *(ushort4*)(out + i) = u;
  }
}

// ------------------------------------------------- LN1 over C + transpose to (B*N, C)
// x: (B=8, C=256, N=4096) f32.  xln: (32768, 256) bf16.
// grid 512: b = blk>>6, n0 = (blk&63)*64.  256 threads.
__global__ __launch_bounds__(256)
void ln1_transpose(const float* __restrict__ x, const float* __restrict__ g,
                   const float* __restrict__ be, u16* __restrict__ xln) {
  int b = blockIdx.x >> 6;
  int n0 = (blockIdx.x & 63) << 6;
  int t = threadIdx.x;
  int w = t >> 6, l = t & 63;
  const float* xb = x + (size_t)b * 256 * 4096 + n0;
  __shared__ float red[8][64];
  __shared__ float mu[64], rs[64];
  __shared__ u16 tile[256][65];
  float s = 0.f, ss = 0.f;
#pragma unroll 8
  for (int i = 0; i < 64; ++i) {
    int c = (w << 6) + i;
    float v = xb[(size_t)c * 4096 + l];
    s += v; ss += v * v;
    tile[c][l] = f2b(v);
  }
  red[w][l] = s;
  red[4 + w][l] = ss;
  __syncthreads();
  if (t < 64) {
    float S = red[0][t] + red[1][t] + red[2][t] + red[3][t];
    float SS = red[4][t] + red[5][t] + red[6][t] + red[7][t];
    float m = S * 0.00390625f;
    float var = SS * 0.00390625f - m * m;
    mu[t] = m;
    rs[t] = rsqrtf(var + 1e-5f);
  }
  __syncthreads();
  int c4 = l << 2;
  float g0 = g[c4], gA = g[c4 + 1], gB = g[c4 + 2], gC = g[c4 + 3];
  float e0 = be[c4], eA = be[c4 + 1], eB = be[c4 + 2], eC = be[c4 + 3];
  u16* orow = xln + ((size_t)(b * 4096 + n0)) * 256 + c4;
#pragma unroll
  for (int jj = 0; jj < 16; ++jj) {
    int pp = (jj << 2) + w;
    float m = mu[pp], r = rs[pp];
    ushort4 o;
    o.x = f2b((b2f(tile[c4 + 0][pp]) - m) * r * g0 + e0);
    o.y = f2b((b2f(tile[c4 + 1][pp]) - m) * r * gA + eA);
    o.z = f2b((b2f(tile[c4 + 2][pp]) - m) * r * gB + eB);
    o.w = f2b((b2f(tile[c4 + 3][pp]) - m) * r * gC + eC);
    *(ushort4*)(orow + (size_t)pp * 256) = o;
  }
}

// ------------------------------------------------- NT bf16 GEMM: C = A * B^T + bias
// A: (M,K) bf16 row-major; B: (Nout,K) bf16 row-major; C: (M,Nout) bf16.
// 128x128 tile, BK=32, 256 threads (4 waves, each 64x64).
__global__ __launch_bounds__(256)
void gemm_bt(const u16* __restrict__ A, const u16* __restrict__ B,
             const float* __restrict__ bias, u16* __restrict__ C,
             int N, int K, int relu) {
  __shared__ u16 As[128 * 32];
  __shared__ u16 Bs[128 * 32];
  int t = threadIdx.x;
  int lane = t & 63, wid = t >> 6;
  int tm = blockIdx.y << 7, tn = blockIdx.x << 7;
  int wm = (wid >> 1) << 6, wn = (wid & 1) << 6;
  int fr = lane & 15, fk = (lane >> 4) << 3;
  f32x4 acc[4][4];
#pragma unroll
  for (int i = 0; i < 4; ++i)
#pragma unroll
    for (int j = 0; j < 4; ++j) acc[i][j] = (f32x4){0.f, 0.f, 0.f, 0.f};

  // staging: thread t handles rows sr and sr+64, 16B of K each
  int sr = t >> 2, sc = (t & 3) << 3;
  const u16* Ag = A + (size_t)(tm + sr) * K + sc;
  const u16* Bg = B + (size_t)(tn + sr) * K + sc;
  u16* As0 = &As[sr * 32 + sc];
  u16* Bs0 = &Bs[sr * 32 + sc];
  size_t rstep = (size_t)64 * K;

  for (int k0 = 0; k0 < K; k0 += 32) {
    uint4 a0 = *(const uint4*)(Ag + k0);
    uint4 a1 = *(const uint4*)(Ag + k0 + rstep);
    uint4 b0 = *(const uint4*)(Bg + k0);
    uint4 b1 = *(const uint4*)(Bg + k0 + rstep);
    __syncthreads();
    *(uint4*)As0 = a0;
    *(uint4*)(As0 + 64 * 32) = a1;
    *(uint4*)Bs0 = b0;
    *(uint4*)(Bs0 + 64 * 32) = b1;
    __syncthreads();
    bf16x8 af[4], bf[4];
#pragma unroll
    for (int mi = 0; mi < 4; ++mi)
      af[mi] = *(const bf16x8*)&As[(wm + mi * 16 + fr) * 32 + fk];
#pragma unroll
    for (int ni = 0; ni < 4; ++ni)
      bf[ni] = *(const bf16x8*)&Bs[(wn + ni * 16 + fr) * 32 + fk];
#pragma unroll
    for (int mi = 0; mi < 4; ++mi)
#pragma unroll
      for (int ni = 0; ni < 4; ++ni)
        acc[mi][ni] = __builtin_amdgcn_mfma_f32_16x16x32_bf16(
            af[mi], bf[ni], acc[mi][ni], 0, 0, 0);
  }

  int rbase = (lane >> 4) << 2;
#pragma unroll
  for (int mi = 0; mi < 4; ++mi) {
#pragma unroll
    for (int ni = 0; ni < 4; ++ni) {
      int col = tn + wn + ni * 16 + fr;
      float bv = bias[col];
#pragma unroll
      for (int r = 0; r < 4; ++r) {
        float v = acc[mi][ni][r] + bv;
        if (relu) v = fmaxf(v, 0.f);
        C[(size_t)(tm + wm + mi * 16 + rbase + r) * N + col] = f2b(v);
      }
    }
  }
}

// ------------------------------------------------- channel-attention S = (Q^T K)/8
// qkv: (32768, 768) bf16 (cols 0:256 q, 256:512 k, 512:768 v)
// Sp: (32 bh, 8 kc, 64 d, 64 e) f32 partials.  grid (8 kc, 32 bh), 256 thr.
__global__ __launch_bounds__(256)
void attn_s(const u16* __restrict__ qkv, float* __restrict__ Sp) {
  int kc = blockIdx.x, bh = blockIdx.y;
  int b = bh >> 2, h = bh & 3;
  int t = threadIdx.x, lane = t & 63, w = t >> 6;
  int fr = lane & 15, fkg = (lane >> 4) << 3;
  const u16* base = qkv + (size_t)b * 4096 * 768;
  int d0 = w << 4;
  f32x4 acc[4];
#pragma unroll
  for (int i = 0; i < 4; ++i) acc[i] = (f32x4){0.f, 0.f, 0.f, 0.f};
  int nbase = kc * 512;
  for (int ks = 0; ks < 16; ++ks) {
    int n = nbase + ks * 32 + fkg;
    const u16* qp = base + (size_t)n * 768 + h * 64;
    const u16* kp = qp + 256;
    bf16x8 aq;
#pragma unroll
    for (int j = 0; j < 8; ++j) aq[j] = (short)qp[(size_t)j * 768 + d0 + fr];
#pragma unroll
    for (int ni = 0; ni < 4; ++ni) {
      bf16x8 bk;
#pragma unroll
      for (int j = 0; j < 8; ++j) bk[j] = (short)kp[(size_t)j * 768 + ni * 16 + fr];
      acc[ni] = __builtin_amdgcn_mfma_f32_16x16x32_bf16(aq, bk, acc[ni], 0, 0, 0);
    }
  }
  float* out = Sp + (size_t)(bh * 8 + kc) * 64 * 64;
  int dr = d0 + ((lane >> 4) << 2);
#pragma unroll
  for (int ni = 0; ni < 4; ++ni)
#pragma unroll
    for (int r = 0; r < 4; ++r)
      out[(dr + r) * 64 + ni * 16 + fr] = acc[ni][r] * 0.125f;
}

// ------------------------------------------------- softmax over e (rows d), 64x64
// grid 32 (bh), 256 thr: thread t owns d = t>>2, 16 e values.
__global__ __launch_bounds__(256)
void attn_softmax(const float* __restrict__ Sp, u16* __restrict__ attn) {
  int bh = blockIdx.x;
  int t = threadIdx.x;
  int d = t >> 2, q = t & 3;
  const float* sp = Sp + (size_t)bh * 8 * 64 * 64;
  float v[16];
#pragma unroll
  for (int i = 0; i < 16; ++i) v[i] = 0.f;
  for (int kc = 0; kc < 8; ++kc) {
    const float* p = sp + kc * 4096 + d * 64 + q * 16;
#pragma unroll
    for (int i = 0; i < 16; i += 4) {
      float4 f = *(const float4*)(p + i);
      v[i] += f.x; v[i + 1] += f.y; v[i + 2] += f.z; v[i + 3] += f.w;
    }
  }
  float m = v[0];
#pragma unroll
  for (int i = 1; i < 16; ++i) m = fmaxf(m, v[i]);
  m = fmaxf(m, __shfl_xor(m, 1));
  m = fmaxf(m, __shfl_xor(m, 2));
  float s = 0.f;
#pragma unroll
  for (int i = 0; i < 16; ++i) { v[i] = expf(v[i] - m); s += v[i]; }
  s += __shfl_xor(s, 1);
  s += __shfl_xor(s, 2);
  float inv = 1.f / s;
  u16* out = attn + (size_t)bh * 4096 + d * 64 + q * 16;
#pragma unroll
  for (int i = 0; i < 16; i += 4) {
    ushort4 u;
    u.x = f2b(v[i] * inv); u.y = f2b(v[i + 1] * inv);
    u.z = f2b(v[i + 2] * inv); u.w = f2b(v[i + 3] * inv);
    *(ushort4*)(out + i) = u;
  }
}

// ------------------------------------------------- AttOut[n,d] = sum_e V[n,e] attn[d,e]
// grid (32 ntile, 32 bh), 256 thr, no LDS (both fragments contiguous 16B).
__global__ __launch_bounds__(256)
void attn_av(const u16* __restrict__ qkv, const u16* __restrict__ attn,
             u16* __restrict__ attnout) {
  int nt = blockIdx.x, bh = blockIdx.y;
  int b = bh >> 2, h = bh & 3;
  int t = threadIdx.x, lane = t & 63, w = t >> 6;
  int fr = lane & 15, fk = (lane >> 4) << 3;
  int n0 = nt * 128 + w * 32;
  const u16* vg = qkv + (size_t)b * 4096 * 768 + 512 + h * 64;
  const u16* at = attn + (size_t)bh * 4096;
  f32x4 acc[2][4];
#pragma unroll
  for (int i = 0; i < 2; ++i)
#pragma unroll
    for (int j = 0; j < 4; ++j) acc[i][j] = (f32x4){0.f, 0.f, 0.f, 0.f};
#pragma unroll
  for (int kk = 0; kk < 2; ++kk) {
    bf16x8 av[2], bv[4];
#pragma unroll
    for (int mi = 0; mi < 2; ++mi)
      av[mi] = *(const bf16x8*)(vg + (size_t)(n0 + mi * 16 + fr) * 768 + kk * 32 + fk);
#pragma unroll
    for (int ni = 0; ni < 4; ++ni)
      bv[ni] = *(const bf16x8*)(at + (size_t)(ni * 16 + fr) * 64 + kk * 32 + fk);
#pragma unroll
    for (int mi = 0; mi < 2; ++mi)
#pragma unroll
      for (int ni = 0; ni < 4; ++ni)
        acc[mi][ni] = __builtin_amdgcn_mfma_f32_16x16x32_bf16(
            av[mi], bv[ni], acc[mi][ni], 0, 0, 0);
  }
  u16* outp = attnout + (size_t)b * 4096 * 256 + h * 64;
  int rbase = (lane >> 4) << 2;
#pragma unroll
  for (int mi = 0; mi < 2; ++mi)
#pragma unroll
    for (int ni = 0; ni < 4; ++ni)
#pragma unroll
      for (int r = 0; r < 4; ++r)
        outp[(size_t)(n0 + mi * 16 + rbase + r) * 256 + ni * 16 + fr] =
            f2b(acc[mi][ni][r]);
}

// ------------------------------------------------- row LayerNorm (256 cols), in-place
// grid 8192, 256 thr: wave per row.
__global__ __launch_bounds__(256)
void ln2_rows(u16* __restrict__ io, const float* __restrict__ g,
              const float* __restrict__ be) {
  int w = threadIdx.x >> 6, lane = threadIdx.x & 63;
  size_t row = (size_t)blockIdx.x * 4 + w;
  u16* p = io + row * 256 + lane * 4;
  ushort4 u = *(ushort4*)p;
  float v0 = b2f(u.x), v1 = b2f(u.y), v2 = b2f(u.z), v3 = b2f(u.w);
  float s = v0 + v1 + v2 + v3;
  float ss = v0 * v0 + v1 * v1 + v2 * v2 + v3 * v3;
#pragma unroll
  for (int off = 1; off < 64; off <<= 1) {
    s += __shfl_xor(s, off);
    ss += __shfl_xor(ss, off);
  }
  float m = s * 0.00390625f;
  float var = ss * 0.00390625f - m * m;
  float r = rsqrtf(var + 1e-5f);
  int c = lane * 4;
  u.x = f2b((v0 - m) * r * g[c] + be[c]);
  u.y = f2b((v1 - m) * r * g[c + 1] + be[c + 1]);
  u.z = f2b((v2 - m) * r * g[c + 2] + be[c + 2]);
  u.w = f2b((v3 - m) * r * g[c + 3] + be[c + 3]);
  *(ushort4*)p = u;
}

// ------------------------------------------------- transpose back + residual
// out[b,c,n] = ffn2[(b*4096+n)*256 + c] + x[b,c,n]   (f32 out)
// grid 2048: b = blk>>8, ct = (blk>>6)&3, ntl = blk&63. 64x64 tile.
__global__ __launch_bounds__(256)
void resid_transpose(const u16* __restrict__ f2o, const float* __restrict__ x,
                     float* __restrict__ out) {
  int blk = blockIdx.x;
  int b = blk >> 8;
  int ct = (blk >> 6) & 3, ntl = blk & 63;
  int c0 = ct << 6, n0 = ntl << 6;
  int t = threadIdx.x;
  __shared__ float ldsT[64][65];
  {
    int n = t >> 2, cq = (t & 3) << 4;
    const u16* src = f2o + (size_t)(b * 4096 + n0 + n) * 256 + c0 + cq;
    union { uint4 v[2]; u16 s[16]; } tmp;
    tmp.v[0] = *(const uint4*)src;
    tmp.v[1] = *(const uint4*)(src + 8);
#pragma unroll
    for (int i = 0; i < 16; ++i) ldsT[cq + i][n] = b2f(tmp.s[i]);
  }
  __syncthreads();
  const float* xb = x + (size_t)b * 256 * 4096;
  float* ob = out + (size_t)b * 256 * 4096;
  int l = t & 63;
#pragma unroll
  for (int i = 0; i < 16; ++i) {
    int c = i * 4 + (t >> 6);
    size_t idx = (size_t)(c0 + c) * 4096 + n0 + l;
    ob[idx] = ldsT[c][l] + xb[idx];
  }
}

// =================================================================== launch
extern "C" void kernel_launch(void* const* d_in, const int* in_sizes, int n_in,
                              void* d_out, int out_size, void* d_ws, size_t ws_size,
                              hipStream_t stream) {
  (void)in_sizes; (void)n_in; (void)out_size; (void)ws_size;
  const float* x      = (const float*)d_in[0];
  const float* w_qkv  = (const float*)d_in[1];
  const float* b_qkv  = (const float*)d_in[2];
  const float* w_proj = (const float*)d_in[3];
  const float* b_proj = (const float*)d_in[4];
  const float* w_ffn1 = (const float*)d_in[5];
  const float* b_ffn1 = (const float*)d_in[6];
  const float* w_ffn2 = (const float*)d_in[7];
  const float* b_ffn2 = (const float*)d_in[8];
  const float* g1  = (const float*)d_in[9];
  const float* be1 = (const float*)d_in[10];
  const float* g2  = (const float*)d_in[11];
  const float* be2 = (const float*)d_in[12];

  u16* p = (u16*)d_ws;
  u16* wq = p;       p += 196608;               // w_qkv bf16 (768x256)
  u16* wp = p;       p += 65536;                // w_proj bf16 (256x256)
  u16* w1 = p;       p += 524288;               // w_ffn1 bf16 (2048x256)
  u16* w2 = p;       p += 524288;               // w_ffn2 bf16 (256x2048)
  u16* xln = p;      p += (size_t)32768 * 256;  // LN1 output (B*N, C)
  u16* qkv = p;      p += (size_t)32768 * 768;  // QKV (B*N, 3C)
  u16* attnw = p;    p += 32 * 64 * 64;         // attention probs (bh,64,64)
  u16* attnout = p;  p += (size_t)32768 * 256;  // PV output (B*N, C)
  u16* projout = p;  p += (size_t)32768 * 256;  // proj out / LN2 in-place
  u16* ffn1 = p;     p += (size_t)8192 * 2048;  // FFN1 chunk (8192, 2048)
  u16* ffn2 = p;     p += (size_t)32768 * 256;  // FFN2 out (B*N, C)
  float* Sp = (float*)p;                        // S partials (32,8,64,64) f32

  cvt_bf16<<<192, 256, 0, stream>>>(w_qkv, wq, 196608);
  cvt_bf16<<<64, 256, 0, stream>>>(w_proj, wp, 65536);
  cvt_bf16<<<512, 256, 0, stream>>>(w_ffn1, w1, 524288);
  cvt_bf16<<<512, 256, 0, stream>>>(w_ffn2, w2, 524288);

  ln1_transpose<<<512, 256, 0, stream>>>(x, g1, be1, xln);

  gemm_bt<<<dim3(6, 256), 256, 0, stream>>>(xln, wq, b_qkv, qkv, 768, 256, 0);

  attn_s<<<dim3(8, 32), 256, 0, stream>>>(qkv, Sp);
  attn_softmax<<<32, 256, 0, stream>>>(Sp, attnw);
  attn_av<<<dim3(32, 32), 256, 0, stream>>>(qkv, attnw, attnout);

  gemm_bt<<<dim3(2, 256), 256, 0, stream>>>(attnout, wp, b_proj, projout, 256, 256, 0);
  ln2_rows<<<8192, 256, 0, stream>>>(projout, g2, be2);

  for (int mc = 0; mc < 4; ++mc) {
    gemm_bt<<<dim3(16, 64), 256, 0, stream>>>(
        projout + (size_t)mc * 8192 * 256, w1, b_ffn1, ffn1, 2048, 256, 1);
    gemm_bt<<<dim3(2, 64), 256, 0, stream>>>(
        ffn1, w2, b_ffn2, ffn2 + (size_t)mc * 8192 * 256, 256, 2048, 0);
  }

  resid_transpose<<<2048, 256, 0, stream>>>(ffn2, x, (float*)d_out);
}

// Round 2
// 336.919 us; speedup vs baseline: 1.3863x; 1.3863x over previous
//
#include <hip/hip_runtime.h>
#include <stdint.h>

typedef unsigned short u16;
typedef __attribute__((ext_vector_type(8))) short bf16x8;
typedef __attribute__((ext_vector_type(4))) float f32x4;

__device__ __forceinline__ u16 f2b(float f) {
  uint32_t x = __builtin_bit_cast(uint32_t, f);
  uint32_t r = (x + 0x7FFFu + ((x >> 16) & 1u)) >> 16;
  return (u16)r;
}
__device__ __forceinline__ float b2f(u16 u) {
  return __builtin_bit_cast(float, ((uint32_t)u) << 16);
}

// async global->LDS, 16B per lane. LDS dest must be wave-uniform;
// HW writes base + lane*16.
__device__ __forceinline__ void gload16(const u16* g, u16* l) {
  __builtin_amdgcn_global_load_lds(
      (const __attribute__((address_space(1))) uint32_t*)g,
      (__attribute__((address_space(3))) uint32_t*)l, 16, 0, 0);
}

// ---------------------------------------------------------------- cvt f32->bf16
__global__ __launch_bounds__(256) void cvt_bf16(const float* __restrict__ in,
                                                u16* __restrict__ out, int n) {
  int i = (blockIdx.x * 256 + threadIdx.x) * 4;
  if (i + 3 < n) {
    float4 f = *(const float4*)(in + i);
    ushort4 u;
    u.x = f2b(f.x); u.y = f2b(f.y); u.z = f2b(f.z); u.w = f2b(f.w);
    *(ushort4*)(out + i) = u;
  }
}

// ------------------------------------------------- LN1 over C + transpose to (B*N, C)
__global__ __launch_bounds__(256)
void ln1_transpose(const float* __restrict__ x, const float* __restrict__ g,
                   const float* __restrict__ be, u16* __restrict__ xln) {
  int b = blockIdx.x >> 6;
  int n0 = (blockIdx.x & 63) << 6;
  int t = threadIdx.x;
  int w = t >> 6, l = t & 63;
  const float* xb = x + (size_t)b * 256 * 4096 + n0;
  __shared__ float red[8][64];
  __shared__ float mu[64], rs[64];
  __shared__ u16 tile[256][65];
  float s = 0.f, ss = 0.f;
#pragma unroll 8
  for (int i = 0; i < 64; ++i) {
    int c = (w << 6) + i;
    float v = xb[(size_t)c * 4096 + l];
    s += v; ss += v * v;
    tile[c][l] = f2b(v);
  }
  red[w][l] = s;
  red[4 + w][l] = ss;
  __syncthreads();
  if (t < 64) {
    float S = red[0][t] + red[1][t] + red[2][t] + red[3][t];
    float SS = red[4][t] + red[5][t] + red[6][t] + red[7][t];
    float m = S * 0.00390625f;
    float var = SS * 0.00390625f - m * m;
    mu[t] = m;
    rs[t] = rsqrtf(var + 1e-5f);
  }
  __syncthreads();
  int c4 = l << 2;
  float g0 = g[c4], gA = g[c4 + 1], gB = g[c4 + 2], gC = g[c4 + 3];
  float e0 = be[c4], eA = be[c4 + 1], eB = be[c4 + 2], eC = be[c4 + 3];
  u16* orow = xln + ((size_t)(b * 4096 + n0)) * 256 + c4;
#pragma unroll
  for (int jj = 0; jj < 16; ++jj) {
    int pp = (jj << 2) + w;
    float m = mu[pp], r = rs[pp];
    ushort4 o;
    o.x = f2b((b2f(tile[c4 + 0][pp]) - m) * r * g0 + e0);
    o.y = f2b((b2f(tile[c4 + 1][pp]) - m) * r * gA + eA);
    o.z = f2b((b2f(tile[c4 + 2][pp]) - m) * r * gB + eB);
    o.w = f2b((b2f(tile[c4 + 3][pp]) - m) * r * gC + eC);
    *(ushort4*)(orow + (size_t)pp * 256) = o;
  }
}

// ------------------------------------------------- NT bf16 GEMM: C = A * B^T + bias
// 128x128 tile, BK=32, 256 threads (4 waves, each 64x64).
// Staging via global_load_lds width-16 (m97 structure, 2 barriers/K-step).
__global__ __launch_bounds__(256)
void gemm_bt(const u16* __restrict__ A, const u16* __restrict__ B,
             const float* __restrict__ bias, u16* __restrict__ C,
             int N, int K, int relu) {
  __shared__ u16 As[128 * 32];
  __shared__ u16 Bs[128 * 32];
  int t = threadIdx.x;
  int lane = t & 63, wid = t >> 6;
  int tm = blockIdx.y << 7, tn = blockIdx.x << 7;
  int wm = (wid >> 1) << 6, wn = (wid & 1) << 6;
  int fr = lane & 15, fk = (lane >> 4) << 3;
  f32x4 acc[4][4];
#pragma unroll
  for (int i = 0; i < 4; ++i)
#pragma unroll
    for (int j = 0; j < 4; ++j) acc[i][j] = (f32x4){0.f, 0.f, 0.f, 0.f};

  // staging: thread t covers 16B at (row = t>>2, kcol = (t&3)*8); LDS linear byte
  // offset = t*16, i.e. wave wid writes [wid*1024, wid*1024+1024).
  int sr = t >> 2, sc = (t & 3) << 3;
  const u16* Ag = A + (size_t)(tm + sr) * K + sc;
  const u16* Bg = B + (size_t)(tn + sr) * K + sc;
  u16* lA = As + wid * 512;   // 1024 B per wave
  u16* lB = Bs + wid * 512;
  size_t rstep = (size_t)64 * K;

  for (int k0 = 0; k0 < K; k0 += 32) {
    __syncthreads();  // all waves done reading LDS from previous step
    gload16(Ag + k0, lA);
    gload16(Ag + k0 + rstep, lA + 2048);
    gload16(Bg + k0, lB);
    gload16(Bg + k0 + rstep, lB + 2048);
    __syncthreads();  // vmcnt(0) drain + barrier: tile staged
    bf16x8 af[4], bf[4];
#pragma unroll
    for (int mi = 0; mi < 4; ++mi)
      af[mi] = *(const bf16x8*)&As[(wm + mi * 16 + fr) * 32 + fk];
#pragma unroll
    for (int ni = 0; ni < 4; ++ni)
      bf[ni] = *(const bf16x8*)&Bs[(wn + ni * 16 + fr) * 32 + fk];
#pragma unroll
    for (int mi = 0; mi < 4; ++mi)
#pragma unroll
      for (int ni = 0; ni < 4; ++ni)
        acc[mi][ni] = __builtin_amdgcn_mfma_f32_16x16x32_bf16(
            af[mi], bf[ni], acc[mi][ni], 0, 0, 0);
  }

  int rbase = (lane >> 4) << 2;
#pragma unroll
  for (int mi = 0; mi < 4; ++mi) {
#pragma unroll
    for (int ni = 0; ni < 4; ++ni) {
      int col = tn + wn + ni * 16 + fr;
      float bv = bias[col];
#pragma unroll
      for (int r = 0; r < 4; ++r) {
        float v = acc[mi][ni][r] + bv;
        if (relu) v = fmaxf(v, 0.f);
        C[(size_t)(tm + wm + mi * 16 + rbase + r) * N + col] = f2b(v);
      }
    }
  }
}

// ------------------------------------------------- channel-attention S = (Q^T K)/8
__global__ __launch_bounds__(256)
void attn_s(const u16* __restrict__ qkv, float* __restrict__ Sp) {
  int kc = blockIdx.x, bh = blockIdx.y;
  int b = bh >> 2, h = bh & 3;
  int t = threadIdx.x, lane = t & 63, w = t >> 6;
  int fr = lane & 15, fkg = (lane >> 4) << 3;
  const u16* base = qkv + (size_t)b * 4096 * 768;
  int d0 = w << 4;
  f32x4 acc[4];
#pragma unroll
  for (int i = 0; i < 4; ++i) acc[i] = (f32x4){0.f, 0.f, 0.f, 0.f};
  int nbase = kc * 512;
  for (int ks = 0; ks < 16; ++ks) {
    int n = nbase + ks * 32 + fkg;
    const u16* qp = base + (size_t)n * 768 + h * 64;
    const u16* kp = qp + 256;
    bf16x8 aq;
#pragma unroll
    for (int j = 0; j < 8; ++j) aq[j] = (short)qp[(size_t)j * 768 + d0 + fr];
#pragma unroll
    for (int ni = 0; ni < 4; ++ni) {
      bf16x8 bk;
#pragma unroll
      for (int j = 0; j < 8; ++j) bk[j] = (short)kp[(size_t)j * 768 + ni * 16 + fr];
      acc[ni] = __builtin_amdgcn_mfma_f32_16x16x32_bf16(aq, bk, acc[ni], 0, 0, 0);
    }
  }
  float* out = Sp + (size_t)(bh * 8 + kc) * 64 * 64;
  int dr = d0 + ((lane >> 4) << 2);
#pragma unroll
  for (int ni = 0; ni < 4; ++ni)
#pragma unroll
    for (int r = 0; r < 4; ++r)
      out[(dr + r) * 64 + ni * 16 + fr] = acc[ni][r] * 0.125f;
}

// ------------------------------------------------- softmax over e (rows d), 64x64
__global__ __launch_bounds__(256)
void attn_softmax(const float* __restrict__ Sp, u16* __restrict__ attn) {
  int bh = blockIdx.x;
  int t = threadIdx.x;
  int d = t >> 2, q = t & 3;
  const float* sp = Sp + (size_t)bh * 8 * 64 * 64;
  float v[16];
#pragma unroll
  for (int i = 0; i < 16; ++i) v[i] = 0.f;
  for (int kc = 0; kc < 8; ++kc) {
    const float* p = sp + kc * 4096 + d * 64 + q * 16;
#pragma unroll
    for (int i = 0; i < 16; i += 4) {
      float4 f = *(const float4*)(p + i);
      v[i] += f.x; v[i + 1] += f.y; v[i + 2] += f.z; v[i + 3] += f.w;
    }
  }
  float m = v[0];
#pragma unroll
  for (int i = 1; i < 16; ++i) m = fmaxf(m, v[i]);
  m = fmaxf(m, __shfl_xor(m, 1));
  m = fmaxf(m, __shfl_xor(m, 2));
  float s = 0.f;
#pragma unroll
  for (int i = 0; i < 16; ++i) { v[i] = expf(v[i] - m); s += v[i]; }
  s += __shfl_xor(s, 1);
  s += __shfl_xor(s, 2);
  float inv = 1.f / s;
  u16* out = attn + (size_t)bh * 4096 + d * 64 + q * 16;
#pragma unroll
  for (int i = 0; i < 16; i += 4) {
    ushort4 u;
    u.x = f2b(v[i] * inv); u.y = f2b(v[i + 1] * inv);
    u.z = f2b(v[i + 2] * inv); u.w = f2b(v[i + 3] * inv);
    *(ushort4*)(out + i) = u;
  }
}

// ------------------------------------------------- AttOut[n,d] = sum_e V[n,e] attn[d,e]
__global__ __launch_bounds__(256)
void attn_av(const u16* __restrict__ qkv, const u16* __restrict__ attn,
             u16* __restrict__ attnout) {
  int nt = blockIdx.x, bh = blockIdx.y;
  int b = bh >> 2, h = bh & 3;
  int t = threadIdx.x, lane = t & 63, w = t >> 6;
  int fr = lane & 15, fk = (lane >> 4) << 3;
  int n0 = nt * 128 + w * 32;
  const u16* vg = qkv + (size_t)b * 4096 * 768 + 512 + h * 64;
  const u16* at = attn + (size_t)bh * 4096;
  f32x4 acc[2][4];
#pragma unroll
  for (int i = 0; i < 2; ++i)
#pragma unroll
    for (int j = 0; j < 4; ++j) acc[i][j] = (f32x4){0.f, 0.f, 0.f, 0.f};
#pragma unroll
  for (int kk = 0; kk < 2; ++kk) {
    bf16x8 av[2], bv[4];
#pragma unroll
    for (int mi = 0; mi < 2; ++mi)
      av[mi] = *(const bf16x8*)(vg + (size_t)(n0 + mi * 16 + fr) * 768 + kk * 32 + fk);
#pragma unroll
    for (int ni = 0; ni < 4; ++ni)
      bv[ni] = *(const bf16x8*)(at + (size_t)(ni * 16 + fr) * 64 + kk * 32 + fk);
#pragma unroll
    for (int mi = 0; mi < 2; ++mi)
#pragma unroll
      for (int ni = 0; ni < 4; ++ni)
        acc[mi][ni] = __builtin_amdgcn_mfma_f32_16x16x32_bf16(
            av[mi], bv[ni], acc[mi][ni], 0, 0, 0);
  }
  u16* outp = attnout + (size_t)b * 4096 * 256 + h * 64;
  int rbase = (lane >> 4) << 2;
#pragma unroll
  for (int mi = 0; mi < 2; ++mi)
#pragma unroll
    for (int ni = 0; ni < 4; ++ni)
#pragma unroll
      for (int r = 0; r < 4; ++r)
        outp[(size_t)(n0 + mi * 16 + rbase + r) * 256 + ni * 16 + fr] =
            f2b(acc[mi][ni][r]);
}

// ------------------------------------------------- row LayerNorm (256 cols), in-place
__global__ __launch_bounds__(256)
void ln2_rows(u16* __restrict__ io, const float* __restrict__ g,
              const float* __restrict__ be) {
  int w = threadIdx.x >> 6, lane = threadIdx.x & 63;
  size_t row = (size_t)blockIdx.x * 4 + w;
  u16* p = io + row * 256 + lane * 4;
  ushort4 u = *(ushort4*)p;
  float v0 = b2f(u.x), v1 = b2f(u.y), v2 = b2f(u.z), v3 = b2f(u.w);
  float s = v0 + v1 + v2 + v3;
  float ss = v0 * v0 + v1 * v1 + v2 * v2 + v3 * v3;
#pragma unroll
  for (int off = 1; off < 64; off <<= 1) {
    s += __shfl_xor(s, off);
    ss += __shfl_xor(ss, off);
  }
  float m = s * 0.00390625f;
  float var = ss * 0.00390625f - m * m;
  float r = rsqrtf(var + 1e-5f);
  int c = lane * 4;
  u.x = f2b((v0 - m) * r * g[c] + be[c]);
  u.y = f2b((v1 - m) * r * g[c + 1] + be[c + 1]);
  u.z = f2b((v2 - m) * r * g[c + 2] + be[c + 2]);
  u.w = f2b((v3 - m) * r * g[c + 3] + be[c + 3]);
  *(ushort4*)p = u;
}

// ------------------------------------------------- transpose back + residual
__global__ __launch_bounds__(256)
void resid_transpose(const u16* __restrict__ f2o, const float* __restrict__ x,
                     float* __restrict__ out) {
  int blk = blockIdx.x;
  int b = blk >> 8;
  int ct = (blk >> 6) & 3, ntl = blk & 63;
  int c0 = ct << 6, n0 = ntl << 6;
  int t = threadIdx.x;
  __shared__ float ldsT[64][65];
  {
    int n = t >> 2, cq = (t & 3) << 4;
    const u16* src = f2o + (size_t)(b * 4096 + n0 + n) * 256 + c0 + cq;
    union { uint4 v[2]; u16 s[16]; } tmp;
    tmp.v[0] = *(const uint4*)src;
    tmp.v[1] = *(const uint4*)(src + 8);
#pragma unroll
    for (int i = 0; i < 16; ++i) ldsT[cq + i][n] = b2f(tmp.s[i]);
  }
  __syncthreads();
  const float* xb = x + (size_t)b * 256 * 4096;
  float* ob = out + (size_t)b * 256 * 4096;
  int l = t & 63;
#pragma unroll
  for (int i = 0; i < 16; ++i) {
    int c = i * 4 + (t >> 6);
    size_t idx = (size_t)(c0 + c) * 4096 + n0 + l;
    ob[idx] = ldsT[c][l] + xb[idx];
  }
}

// =================================================================== launch
extern "C" void kernel_launch(void* const* d_in, const int* in_sizes, int n_in,
                              void* d_out, int out_size, void* d_ws, size_t ws_size,
                              hipStream_t stream) {
  (void)in_sizes; (void)n_in; (void)out_size;
  const float* x      = (const float*)d_in[0];
  const float* w_qkv  = (const float*)d_in[1];
  const float* b_qkv  = (const float*)d_in[2];
  const float* w_proj = (const float*)d_in[3];
  const float* b_proj = (const float*)d_in[4];
  const float* w_ffn1 = (const float*)d_in[5];
  const float* b_ffn1 = (const float*)d_in[6];
  const float* w_ffn2 = (const float*)d_in[7];
  const float* b_ffn2 = (const float*)d_in[8];
  const float* g1  = (const float*)d_in[9];
  const float* be1 = (const float*)d_in[10];
  const float* g2  = (const float*)d_in[11];
  const float* be2 = (const float*)d_in[12];

  u16* p = (u16*)d_ws;
  u16* wq = p;       p += 196608;               // w_qkv bf16 (768x256)
  u16* wp = p;       p += 65536;                // w_proj bf16 (256x256)
  u16* w1 = p;       p += 524288;               // w_ffn1 bf16 (2048x256)
  u16* w2 = p;       p += 524288;               // w_ffn2 bf16 (256x2048)
  u16* xln = p;      p += (size_t)32768 * 256;  // LN1 output (B*N, C)
  u16* qkv = p;      p += (size_t)32768 * 768;  // QKV (B*N, 3C)
  u16* attnw = p;    p += 32 * 64 * 64;         // attention probs (bh,64,64)
  u16* attnout = p;  p += (size_t)32768 * 256;  // PV output (B*N, C)
  u16* projout = p;  p += (size_t)32768 * 256;  // proj out / LN2 in-place
  u16* ffn2 = p;     p += (size_t)32768 * 256;  // FFN2 out (B*N, C)
  float* Sp = (float*)p; p += (size_t)2 * 32 * 8 * 64 * 64;  // S partials f32
  u16* ffn1 = p;                                // FFN1 buffer (variable size)

  size_t fixed = (size_t)(p - (u16*)d_ws);
  // pick fewest FFN M-chunks that fit the workspace
  int nc = 4;
  if (ws_size >= (fixed + (size_t)32768 * 2048) * 2) nc = 1;
  else if (ws_size >= (fixed + (size_t)16384 * 2048) * 2) nc = 2;
  int Mc = 32768 / nc;

  cvt_bf16<<<192, 256, 0, stream>>>(w_qkv, wq, 196608);
  cvt_bf16<<<64, 256, 0, stream>>>(w_proj, wp, 65536);
  cvt_bf16<<<512, 256, 0, stream>>>(w_ffn1, w1, 524288);
  cvt_bf16<<<512, 256, 0, stream>>>(w_ffn2, w2, 524288);

  ln1_transpose<<<512, 256, 0, stream>>>(x, g1, be1, xln);

  gemm_bt<<<dim3(6, 256), 256, 0, stream>>>(xln, wq, b_qkv, qkv, 768, 256, 0);

  attn_s<<<dim3(8, 32), 256, 0, stream>>>(qkv, Sp);
  attn_softmax<<<32, 256, 0, stream>>>(Sp, attnw);
  attn_av<<<dim3(32, 32), 256, 0, stream>>>(qkv, attnw, attnout);

  gemm_bt<<<dim3(2, 256), 256, 0, stream>>>(attnout, wp, b_proj, projout, 256, 256, 0);
  ln2_rows<<<8192, 256, 0, stream>>>(projout, g2, be2);

  for (int mc = 0; mc < nc; ++mc) {
    gemm_bt<<<dim3(16, Mc / 128), 256, 0, stream>>>(
        projout + (size_t)mc * Mc * 256, w1, b_ffn1, ffn1, 2048, 256, 1);
    gemm_bt<<<dim3(2, Mc / 128), 256, 0, stream>>>(
        ffn1, w2, b_ffn2, ffn2 + (size_t)mc * Mc * 256, 256, 2048, 0);
  }

  resid_transpose<<<2048, 256, 0, stream>>>(ffn2, x, (float*)d_out);
}

// Round 5
// 330.616 us; speedup vs baseline: 1.4128x; 1.0191x over previous
//
#include <hip/hip_runtime.h>
#include <stdint.h>

typedef unsigned short u16;
typedef __attribute__((ext_vector_type(8))) short bf16x8;
typedef __attribute__((ext_vector_type(4))) float f32x4;

__device__ __forceinline__ u16 f2b(float f) {
  uint32_t x = __builtin_bit_cast(uint32_t, f);
  uint32_t r = (x + 0x7FFFu + ((x >> 16) & 1u)) >> 16;
  return (u16)r;
}
__device__ __forceinline__ float b2f(u16 u) {
  return __builtin_bit_cast(float, ((uint32_t)u) << 16);
}

// async global->LDS, 16B per lane. LDS dest is wave-uniform base; HW writes
// base + lane*16.
__device__ __forceinline__ void gload16(const u16* g, u16* l) {
  __builtin_amdgcn_global_load_lds(
      (const __attribute__((address_space(1))) uint32_t*)g,
      (__attribute__((address_space(3))) uint32_t*)l, 16, 0, 0);
}

// ---------------------------------------------------------------- cvt f32->bf16
__global__ __launch_bounds__(256) void cvt_bf16(const float* __restrict__ in,
                                                u16* __restrict__ out, int n) {
  int i = (blockIdx.x * 256 + threadIdx.x) * 4;
  if (i + 3 < n) {
    float4 f = *(const float4*)(in + i);
    ushort4 u;
    u.x = f2b(f.x); u.y = f2b(f.y); u.z = f2b(f.z); u.w = f2b(f.w);
    *(ushort4*)(out + i) = u;
  }
}

// ------------------------------------------------- LN1 over C + transpose to (B*N, C)
__global__ __launch_bounds__(256)
void ln1_transpose(const float* __restrict__ x, const float* __restrict__ g,
                   const float* __restrict__ be, u16* __restrict__ xln) {
  int b = blockIdx.x >> 6;
  int n0 = (blockIdx.x & 63) << 6;
  int t = threadIdx.x;
  int w = t >> 6, l = t & 63;
  const float* xb = x + (size_t)b * 256 * 4096 + n0;
  __shared__ float red[8][64];
  __shared__ float mu[64], rs[64];
  __shared__ u16 tile[256][65];
  float s = 0.f, ss = 0.f;
#pragma unroll 8
  for (int i = 0; i < 64; ++i) {
    int c = (w << 6) + i;
    float v = xb[(size_t)c * 4096 + l];
    s += v; ss += v * v;
    tile[c][l] = f2b(v);
  }
  red[w][l] = s;
  red[4 + w][l] = ss;
  __syncthreads();
  if (t < 64) {
    float S = red[0][t] + red[1][t] + red[2][t] + red[3][t];
    float SS = red[4][t] + red[5][t] + red[6][t] + red[7][t];
    float m = S * 0.00390625f;
    float var = SS * 0.00390625f - m * m;
    mu[t] = m;
    rs[t] = rsqrtf(var + 1e-5f);
  }
  __syncthreads();
  int c4 = l << 2;
  float g0 = g[c4], gA = g[c4 + 1], gB = g[c4 + 2], gC = g[c4 + 3];
  float e0 = be[c4], eA = be[c4 + 1], eB = be[c4 + 2], eC = be[c4 + 3];
  u16* orow = xln + ((size_t)(b * 4096 + n0)) * 256 + c4;
#pragma unroll
  for (int jj = 0; jj < 16; ++jj) {
    int pp = (jj << 2) + w;
    float m = mu[pp], r = rs[pp];
    ushort4 o;
    o.x = f2b((b2f(tile[c4 + 0][pp]) - m) * r * g0 + e0);
    o.y = f2b((b2f(tile[c4 + 1][pp]) - m) * r * gA + eA);
    o.z = f2b((b2f(tile[c4 + 2][pp]) - m) * r * gB + eB);
    o.w = f2b((b2f(tile[c4 + 3][pp]) - m) * r * gC + eC);
    *(ushort4*)(orow + (size_t)pp * 256) = o;
  }
}

// ------------------------------------------------- NT bf16 GEMM: C = A * B^T + bias
// 128x128 tile, BK=32, 256 threads (4 waves, each 64x64).
// 2-phase schedule: double-buffered LDS, next tile's global_load_lds issued
// BEFORE current tile's ds_read+MFMA, ONE __syncthreads per K-step (its
// implicit vmcnt(0) drain lands after compute -> load latency hidden).
__global__ __launch_bounds__(256)
void gemm_bt(const u16* __restrict__ A, const u16* __restrict__ B,
             const float* __restrict__ bias, u16* __restrict__ C,
             int N, int K, int relu) {
  __shared__ u16 As[2][128 * 32];
  __shared__ u16 Bs[2][128 * 32];
  int t = threadIdx.x;
  int lane = t & 63, wid = t >> 6;
  int tm = blockIdx.y << 7, tn = blockIdx.x << 7;
  int wm = (wid >> 1) << 6, wn = (wid & 1) << 6;
  int fr = lane & 15, fk = (lane >> 4) << 3;
  f32x4 acc[4][4];
#pragma unroll
  for (int i = 0; i < 4; ++i)
#pragma unroll
    for (int j = 0; j < 4; ++j) acc[i][j] = (f32x4){0.f, 0.f, 0.f, 0.f};

  // staging: thread t covers 16B at (row = t>>2, kcol = (t&3)*8); LDS linear
  // byte offset = t*16, i.e. wave wid writes [wid*1024, wid*1024+1024).
  int sr = t >> 2, sc = (t & 3) << 3;
  const u16* Ag = A + (size_t)(tm + sr) * K + sc;
  const u16* Bg = B + (size_t)(tn + sr) * K + sc;
  size_t rstep = (size_t)64 * K;
  int wo = wid * 512;  // wave's 1024-B LDS chunk (in u16)

  // prologue: stage k=0 into buf 0
  gload16(Ag, As[0] + wo);
  gload16(Ag + rstep, As[0] + wo + 2048);
  gload16(Bg, Bs[0] + wo);
  gload16(Bg + rstep, Bs[0] + wo + 2048);
  __syncthreads();

  int buf = 0;
  for (int k0 = 0; k0 < K; k0 += 32) {
    // issue next tile's loads into the other buffer (in flight during MFMA)
    if (k0 + 32 < K) {
      int nb = buf ^ 1;
      gload16(Ag + k0 + 32, As[nb] + wo);
      gload16(Ag + k0 + 32 + rstep, As[nb] + wo + 2048);
      gload16(Bg + k0 + 32, Bs[nb] + wo);
      gload16(Bg + k0 + 32 + rstep, Bs[nb] + wo + 2048);
    }
    bf16x8 af[4], bf[4];
#pragma unroll
    for (int mi = 0; mi < 4; ++mi)
      af[mi] = *(const bf16x8*)&As[buf][(wm + mi * 16 + fr) * 32 + fk];
#pragma unroll
    for (int ni = 0; ni < 4; ++ni)
      bf[ni] = *(const bf16x8*)&Bs[buf][(wn + ni * 16 + fr) * 32 + fk];
#pragma unroll
    for (int mi = 0; mi < 4; ++mi)
#pragma unroll
      for (int ni = 0; ni < 4; ++ni)
        acc[mi][ni] = __builtin_amdgcn_mfma_f32_16x16x32_bf16(
            af[mi], bf[ni], acc[mi][ni], 0, 0, 0);
    __syncthreads();  // drains vmcnt (next tile staged) + lgkm; protects bufs
    buf ^= 1;
  }

  int rbase = (lane >> 4) << 2;
#pragma unroll
  for (int mi = 0; mi < 4; ++mi) {
#pragma unroll
    for (int ni = 0; ni < 4; ++ni) {
      int col = tn + wn + ni * 16 + fr;
      float bv = bias[col];
#pragma unroll
      for (int r = 0; r < 4; ++r) {
        float v = acc[mi][ni][r] + bv;
        if (relu) v = fmaxf(v, 0.f);
        C[(size_t)(tm + wm + mi * 16 + rbase + r) * N + col] = f2b(v);
      }
    }
  }
}

// ------------------------------------------------- channel-attention S = (Q^T K)/8
__global__ __launch_bounds__(256)
void attn_s(const u16* __restrict__ qkv, float* __restrict__ Sp) {
  int kc = blockIdx.x, bh = blockIdx.y;
  int b = bh >> 2, h = bh & 3;
  int t = threadIdx.x, lane = t & 63, w = t >> 6;
  int fr = lane & 15, fkg = (lane >> 4) << 3;
  const u16* base = qkv + (size_t)b * 4096 * 768;
  int d0 = w << 4;
  f32x4 acc[4];
#pragma unroll
  for (int i = 0; i < 4; ++i) acc[i] = (f32x4){0.f, 0.f, 0.f, 0.f};
  int nbase = kc * 512;
  for (int ks = 0; ks < 16; ++ks) {
    int n = nbase + ks * 32 + fkg;
    const u16* qp = base + (size_t)n * 768 + h * 64;
    const u16* kp = qp + 256;
    bf16x8 aq;
#pragma unroll
    for (int j = 0; j < 8; ++j) aq[j] = (short)qp[(size_t)j * 768 + d0 + fr];
#pragma unroll
    for (int ni = 0; ni < 4; ++ni) {
      bf16x8 bk;
#pragma unroll
      for (int j = 0; j < 8; ++j) bk[j] = (short)kp[(size_t)j * 768 + ni * 16 + fr];
      acc[ni] = __builtin_amdgcn_mfma_f32_16x16x32_bf16(aq, bk, acc[ni], 0, 0, 0);
    }
  }
  float* out = Sp + (size_t)(bh * 8 + kc) * 64 * 64;
  int dr = d0 + ((lane >> 4) << 2);
#pragma unroll
  for (int ni = 0; ni < 4; ++ni)
#pragma unroll
    for (int r = 0; r < 4; ++r)
      out[(dr + r) * 64 + ni * 16 + fr] = acc[ni][r] * 0.125f;
}

// ------------------------------------------------- softmax over e (rows d), 64x64
__global__ __launch_bounds__(256)
void attn_softmax(const float* __restrict__ Sp, u16* __restrict__ attn) {
  int bh = blockIdx.x;
  int t = threadIdx.x;
  int d = t >> 2, q = t & 3;
  const float* sp = Sp + (size_t)bh * 8 * 64 * 64;
  float v[16];
#pragma unroll
  for (int i = 0; i < 16; ++i) v[i] = 0.f;
  for (int kc = 0; kc < 8; ++kc) {
    const float* p = sp + kc * 4096 + d * 64 + q * 16;
#pragma unroll
    for (int i = 0; i < 16; i += 4) {
      float4 f = *(const float4*)(p + i);
      v[i] += f.x; v[i + 1] += f.y; v[i + 2] += f.z; v[i + 3] += f.w;
    }
  }
  float m = v[0];
#pragma unroll
  for (int i = 1; i < 16; ++i) m = fmaxf(m, v[i]);
  m = fmaxf(m, __shfl_xor(m, 1));
  m = fmaxf(m, __shfl_xor(m, 2));
  float s = 0.f;
#pragma unroll
  for (int i = 0; i < 16; ++i) { v[i] = expf(v[i] - m); s += v[i]; }
  s += __shfl_xor(s, 1);
  s += __shfl_xor(s, 2);
  float inv = 1.f / s;
  u16* out = attn + (size_t)bh * 4096 + d * 64 + q * 16;
#pragma unroll
  for (int i = 0; i < 16; i += 4) {
    ushort4 u;
    u.x = f2b(v[i] * inv); u.y = f2b(v[i + 1] * inv);
    u.z = f2b(v[i + 2] * inv); u.w = f2b(v[i + 3] * inv);
    *(ushort4*)(out + i) = u;
  }
}

// ------------------------------------------------- AttOut[n,d] = sum_e V[n,e] attn[d,e]
__global__ __launch_bounds__(256)
void attn_av(const u16* __restrict__ qkv, const u16* __restrict__ attn,
             u16* __restrict__ attnout) {
  int nt = blockIdx.x, bh = blockIdx.y;
  int b = bh >> 2, h = bh & 3;
  int t = threadIdx.x, lane = t & 63, w = t >> 6;
  int fr = lane & 15, fk = (lane >> 4) << 3;
  int n0 = nt * 128 + w * 32;
  const u16* vg = qkv + (size_t)b * 4096 * 768 + 512 + h * 64;
  const u16* at = attn + (size_t)bh * 4096;
  f32x4 acc[2][4];
#pragma unroll
  for (int i = 0; i < 2; ++i)
#pragma unroll
    for (int j = 0; j < 4; ++j) acc[i][j] = (f32x4){0.f, 0.f, 0.f, 0.f};
#pragma unroll
  for (int kk = 0; kk < 2; ++kk) {
    bf16x8 av[2], bv[4];
#pragma unroll
    for (int mi = 0; mi < 2; ++mi)
      av[mi] = *(const bf16x8*)(vg + (size_t)(n0 + mi * 16 + fr) * 768 + kk * 32 + fk);
#pragma unroll
    for (int ni = 0; ni < 4; ++ni)
      bv[ni] = *(const bf16x8*)(at + (size_t)(ni * 16 + fr) * 64 + kk * 32 + fk);
#pragma unroll
    for (int mi = 0; mi < 2; ++mi)
#pragma unroll
      for (int ni = 0; ni < 4; ++ni)
        acc[mi][ni] = __builtin_amdgcn_mfma_f32_16x16x32_bf16(
            av[mi], bv[ni], acc[mi][ni], 0, 0, 0);
  }
  u16* outp = attnout + (size_t)b * 4096 * 256 + h * 64;
  int rbase = (lane >> 4) << 2;
#pragma unroll
  for (int mi = 0; mi < 2; ++mi)
#pragma unroll
    for (int ni = 0; ni < 4; ++ni)
#pragma unroll
      for (int r = 0; r < 4; ++r)
        outp[(size_t)(n0 + mi * 16 + rbase + r) * 256 + ni * 16 + fr] =
            f2b(acc[mi][ni][r]);
}

// ------------------------------------------------- row LayerNorm (256 cols), in-place
__global__ __launch_bounds__(256)
void ln2_rows(u16* __restrict__ io, const float* __restrict__ g,
              const float* __restrict__ be) {
  int w = threadIdx.x >> 6, lane = threadIdx.x & 63;
  size_t row = (size_t)blockIdx.x * 4 + w;
  u16* p = io + row * 256 + lane * 4;
  ushort4 u = *(ushort4*)p;
  float v0 = b2f(u.x), v1 = b2f(u.y), v2 = b2f(u.z), v3 = b2f(u.w);
  float s = v0 + v1 + v2 + v3;
  float ss = v0 * v0 + v1 * v1 + v2 * v2 + v3 * v3;
#pragma unroll
  for (int off = 1; off < 64; off <<= 1) {
    s += __shfl_xor(s, off);
    ss += __shfl_xor(ss, off);
  }
  float m = s * 0.00390625f;
  float var = ss * 0.00390625f - m * m;
  float r = rsqrtf(var + 1e-5f);
  int c = lane * 4;
  u.x = f2b((v0 - m) * r * g[c] + be[c]);
  u.y = f2b((v1 - m) * r * g[c + 1] + be[c + 1]);
  u.z = f2b((v2 - m) * r * g[c + 2] + be[c + 2]);
  u.w = f2b((v3 - m) * r * g[c + 3] + be[c + 3]);
  *(ushort4*)p = u;
}

// ------------------------------------------------- transpose back + residual
__global__ __launch_bounds__(256)
void resid_transpose(const u16* __restrict__ f2o, const float* __restrict__ x,
                     float* __restrict__ out) {
  int blk = blockIdx.x;
  int b = blk >> 8;
  int ct = (blk >> 6) & 3, ntl = blk & 63;
  int c0 = ct << 6, n0 = ntl << 6;
  int t = threadIdx.x;
  __shared__ float ldsT[64][65];
  {
    int n = t >> 2, cq = (t & 3) << 4;
    const u16* src = f2o + (size_t)(b * 4096 + n0 + n) * 256 + c0 + cq;
    union { uint4 v[2]; u16 s[16]; } tmp;
    tmp.v[0] = *(const uint4*)src;
    tmp.v[1] = *(const uint4*)(src + 8);
#pragma unroll
    for (int i = 0; i < 16; ++i) ldsT[cq + i][n] = b2f(tmp.s[i]);
  }
  __syncthreads();
  const float* xb = x + (size_t)b * 256 * 4096;
  float* ob = out + (size_t)b * 256 * 4096;
  int l = t & 63;
#pragma unroll
  for (int i = 0; i < 16; ++i) {
    int c = i * 4 + (t >> 6);
    size_t idx = (size_t)(c0 + c) * 4096 + n0 + l;
    ob[idx] = ldsT[c][l] + xb[idx];
  }
}

// =================================================================== launch
extern "C" void kernel_launch(void* const* d_in, const int* in_sizes, int n_in,
                              void* d_out, int out_size, void* d_ws, size_t ws_size,
                              hipStream_t stream) {
  (void)in_sizes; (void)n_in; (void)out_size;
  const float* x      = (const float*)d_in[0];
  const float* w_qkv  = (const float*)d_in[1];
  const float* b_qkv  = (const float*)d_in[2];
  const float* w_proj = (const float*)d_in[3];
  const float* b_proj = (const float*)d_in[4];
  const float* w_ffn1 = (const float*)d_in[5];
  const float* b_ffn1 = (const float*)d_in[6];
  const float* w_ffn2 = (const float*)d_in[7];
  const float* b_ffn2 = (const float*)d_in[8];
  const float* g1  = (const float*)d_in[9];
  const float* be1 = (const float*)d_in[10];
  const float* g2  = (const float*)d_in[11];
  const float* be2 = (const float*)d_in[12];

  u16* p = (u16*)d_ws;
  u16* wq = p;       p += 196608;               // w_qkv bf16 (768x256)
  u16* wp = p;       p += 65536;                // w_proj bf16 (256x256)
  u16* w1 = p;       p += 524288;               // w_ffn1 bf16 (2048x256)
  u16* w2 = p;       p += 524288;               // w_ffn2 bf16 (256x2048)
  u16* xln = p;      p += (size_t)32768 * 256;  // LN1 output (B*N, C)
  u16* qkv = p;      p += (size_t)32768 * 768;  // QKV (B*N, 3C)
  u16* attnw = p;    p += 32 * 64 * 64;         // attention probs (bh,64,64)
  u16* attnout = p;  p += (size_t)32768 * 256;  // PV output (B*N, C)
  u16* projout = p;  p += (size_t)32768 * 256;  // proj out / LN2 in-place
  u16* ffn2 = p;     p += (size_t)32768 * 256;  // FFN2 out (B*N, C)
  float* Sp = (float*)p; p += (size_t)2 * 32 * 8 * 64 * 64;  // S partials f32
  u16* ffn1 = p;                                // FFN1 buffer (variable size)

  size_t fixed = (size_t)(p - (u16*)d_ws);
  // pick fewest FFN M-chunks that fit the workspace
  int nc = 4;
  if (ws_size >= (fixed + (size_t)32768 * 2048) * 2) nc = 1;
  else if (ws_size >= (fixed + (size_t)16384 * 2048) * 2) nc = 2;
  int Mc = 32768 / nc;

  cvt_bf16<<<192, 256, 0, stream>>>(w_qkv, wq, 196608);
  cvt_bf16<<<64, 256, 0, stream>>>(w_proj, wp, 65536);
  cvt_bf16<<<512, 256, 0, stream>>>(w_ffn1, w1, 524288);
  cvt_bf16<<<512, 256, 0, stream>>>(w_ffn2, w2, 524288);

  ln1_transpose<<<512, 256, 0, stream>>>(x, g1, be1, xln);

  gemm_bt<<<dim3(6, 256), 256, 0, stream>>>(xln, wq, b_qkv, qkv, 768, 256, 0);

  attn_s<<<dim3(8, 32), 256, 0, stream>>>(qkv, Sp);
  attn_softmax<<<32, 256, 0, stream>>>(Sp, attnw);
  attn_av<<<dim3(32, 32), 256, 0, stream>>>(qkv, attnw, attnout);

  gemm_bt<<<dim3(2, 256), 256, 0, stream>>>(attnout, wp, b_proj, projout, 256, 256, 0);
  ln2_rows<<<8192, 256, 0, stream>>>(projout, g2, be2);

  for (int mc = 0; mc < nc; ++mc) {
    gemm_bt<<<dim3(16, Mc / 128), 256, 0, stream>>>(
        projout + (size_t)mc * Mc * 256, w1, b_ffn1, ffn1, 2048, 256, 1);
    gemm_bt<<<dim3(2, Mc / 128), 256, 0, stream>>>(
        ffn1, w2, b_ffn2, ffn2 + (size_t)mc * Mc * 256, 256, 2048, 0);
  }

  resid_transpose<<<2048, 256, 0, stream>>>(ffn2, x, (float*)d_out);
}

// Round 8
// 326.106 us; speedup vs baseline: 1.4323x; 1.0138x over previous
//
#include <hip/hip_runtime.h>
#include <stdint.h>

typedef unsigned short u16;
typedef __attribute__((ext_vector_type(8))) short bf16x8;
typedef __attribute__((ext_vector_type(4))) float f32x4;

__device__ __forceinline__ u16 f2b(float f) {
  uint32_t x = __builtin_bit_cast(uint32_t, f);
  uint32_t r = (x + 0x7FFFu + ((x >> 16) & 1u)) >> 16;
  return (u16)r;
}
__device__ __forceinline__ float b2f(u16 u) {
  return __builtin_bit_cast(float, ((uint32_t)u) << 16);
}

// async global->LDS, 16B per lane. LDS dest is wave-uniform base; HW writes
// base + lane*16.
__device__ __forceinline__ void gload16(const u16* g, u16* l) {
  __builtin_amdgcn_global_load_lds(
      (const __attribute__((address_space(1))) uint32_t*)g,
      (__attribute__((address_space(3))) uint32_t*)l, 16, 0, 0);
}

// ---------------------------------------------------------------- cvt f32->bf16
__global__ __launch_bounds__(256) void cvt_bf16(const float* __restrict__ in,
                                                u16* __restrict__ out, int n) {
  int i = (blockIdx.x * 256 + threadIdx.x) * 4;
  if (i + 3 < n) {
    float4 f = *(const float4*)(in + i);
    ushort4 u;
    u.x = f2b(f.x); u.y = f2b(f.y); u.z = f2b(f.z); u.w = f2b(f.w);
    *(ushort4*)(out + i) = u;
  }
}

// ------------------------------------------------- LN1 over C + transpose to (B*N, C)
__global__ __launch_bounds__(256)
void ln1_transpose(const float* __restrict__ x, const float* __restrict__ g,
                   const float* __restrict__ be, u16* __restrict__ xln) {
  int b = blockIdx.x >> 6;
  int n0 = (blockIdx.x & 63) << 6;
  int t = threadIdx.x;
  int w = t >> 6, l = t & 63;
  const float* xb = x + (size_t)b * 256 * 4096 + n0;
  __shared__ float red[8][64];
  __shared__ float mu[64], rs[64];
  __shared__ u16 tile[256][65];
  float s = 0.f, ss = 0.f;
#pragma unroll 8
  for (int i = 0; i < 64; ++i) {
    int c = (w << 6) + i;
    float v = xb[(size_t)c * 4096 + l];
    s += v; ss += v * v;
    tile[c][l] = f2b(v);
  }
  red[w][l] = s;
  red[4 + w][l] = ss;
  __syncthreads();
  if (t < 64) {
    float S = red[0][t] + red[1][t] + red[2][t] + red[3][t];
    float SS = red[4][t] + red[5][t] + red[6][t] + red[7][t];
    float m = S * 0.00390625f;
    float var = SS * 0.00390625f - m * m;
    mu[t] = m;
    rs[t] = rsqrtf(var + 1e-5f);
  }
  __syncthreads();
  int c4 = l << 2;
  float g0 = g[c4], gA = g[c4 + 1], gB = g[c4 + 2], gC = g[c4 + 3];
  float e0 = be[c4], eA = be[c4 + 1], eB = be[c4 + 2], eC = be[c4 + 3];
  u16* orow = xln + ((size_t)(b * 4096 + n0)) * 256 + c4;
#pragma unroll
  for (int jj = 0; jj < 16; ++jj) {
    int pp = (jj << 2) + w;
    float m = mu[pp], r = rs[pp];
    ushort4 o;
    o.x = f2b((b2f(tile[c4 + 0][pp]) - m) * r * g0 + e0);
    o.y = f2b((b2f(tile[c4 + 1][pp]) - m) * r * gA + eA);
    o.z = f2b((b2f(tile[c4 + 2][pp]) - m) * r * gB + eB);
    o.w = f2b((b2f(tile[c4 + 3][pp]) - m) * r * gC + eC);
    *(ushort4*)(orow + (size_t)pp * 256) = o;
  }
}

// ------------------------------------------------- NT bf16 GEMM: C = A * B^T + bias
// 128x128 tile, BK=32, 256 threads (4 waves, each 64x64).
// T4 pipeline: 3-deep LDS buffering, counted s_waitcnt vmcnt(8/4/0) + raw
// s_barrier — prefetched loads stay in flight across barriers; no vmcnt(0)
// drain in the main loop. Tile k+3 reuses buf[k%3], so a second barrier
// (after each wave's lgkmcnt(0)) protects the ds_reads.
__global__ __launch_bounds__(256)
void gemm_bt(const u16* __restrict__ A, const u16* __restrict__ B,
             const float* __restrict__ bias, u16* __restrict__ C,
             int N, int K, int relu) {
  __shared__ u16 As[3][128 * 32];
  __shared__ u16 Bs[3][128 * 32];
  int t = threadIdx.x;
  int lane = t & 63, wid = t >> 6;
  int tm = blockIdx.y << 7, tn = blockIdx.x << 7;
  int wm = (wid >> 1) << 6, wn = (wid & 1) << 6;
  int fr = lane & 15, fk = (lane >> 4) << 3;
  f32x4 acc[4][4];
#pragma unroll
  for (int i = 0; i < 4; ++i)
#pragma unroll
    for (int j = 0; j < 4; ++j) acc[i][j] = (f32x4){0.f, 0.f, 0.f, 0.f};

  // staging: thread t covers 16B at (row = t>>2, kcol = (t&3)*8); LDS linear
  // byte offset = t*16, i.e. wave wid writes [wid*1024, wid*1024+1024).
  int sr = t >> 2, sc = (t & 3) << 3;
  const u16* Ag = A + (size_t)(tm + sr) * K + sc;
  const u16* Bg = B + (size_t)(tn + sr) * K + sc;
  size_t rstep = (size_t)64 * K;
  int wo = wid * 512;  // wave's 1024-B LDS chunk (in u16)

#define STAGE(kt, bi)                                    \
  do {                                                   \
    int off_ = (kt) << 5;                                \
    gload16(Ag + off_, As[bi] + wo);                     \
    gload16(Ag + off_ + rstep, As[bi] + wo + 2048);      \
    gload16(Bg + off_, Bs[bi] + wo);                     \
    gload16(Bg + off_ + rstep, Bs[bi] + wo + 2048);      \
  } while (0)

  int nk = K >> 5;  // K-steps (>=8 for all our shapes)
  // prologue: 3 tiles in flight (12 loads/thread)
  STAGE(0, 0);
  STAGE(1, 1);
  STAGE(2, 2);

  int buf = 0;
  for (int k = 0; k < nk; ++k) {
    int rem = nk - 1 - k;
    // wait for tile k's 4 loads only (oldest retire in order, m135)
    if (rem >= 2)      asm volatile("s_waitcnt vmcnt(8)" ::: "memory");
    else if (rem == 1) asm volatile("s_waitcnt vmcnt(4)" ::: "memory");
    else               asm volatile("s_waitcnt vmcnt(0)" ::: "memory");
    __builtin_amdgcn_s_barrier();        // tile k staged by ALL waves
    __builtin_amdgcn_sched_barrier(0);   // no ds_read hoists above barrier

    bf16x8 af[4], bf[4];
#pragma unroll
    for (int mi = 0; mi < 4; ++mi)
      af[mi] = *(const bf16x8*)&As[buf][(wm + mi * 16 + fr) * 32 + fk];
#pragma unroll
    for (int ni = 0; ni < 4; ++ni)
      bf[ni] = *(const bf16x8*)&Bs[buf][(wn + ni * 16 + fr) * 32 + fk];

    asm volatile("s_waitcnt lgkmcnt(0)" ::: "memory");  // my reads in regs
    __builtin_amdgcn_sched_barrier(0);   // rule 18: pin before barrier
    __builtin_amdgcn_s_barrier();        // ALL waves done reading buf
    __builtin_amdgcn_sched_barrier(0);   // stage must not hoist above

    if (k + 3 < nk) STAGE(k + 3, buf);   // overwrite just-consumed buffer

#pragma unroll
    for (int mi = 0; mi < 4; ++mi)
#pragma unroll
      for (int ni = 0; ni < 4; ++ni)
        acc[mi][ni] = __builtin_amdgcn_mfma_f32_16x16x32_bf16(
            af[mi], bf[ni], acc[mi][ni], 0, 0, 0);

    buf = (buf == 2) ? 0 : buf + 1;
  }
#undef STAGE

  int rbase = (lane >> 4) << 2;
#pragma unroll
  for (int mi = 0; mi < 4; ++mi) {
#pragma unroll
    for (int ni = 0; ni < 4; ++ni) {
      int col = tn + wn + ni * 16 + fr;
      float bv = bias[col];
#pragma unroll
      for (int r = 0; r < 4; ++r) {
        float v = acc[mi][ni][r] + bv;
        if (relu) v = fmaxf(v, 0.f);
        C[(size_t)(tm + wm + mi * 16 + rbase + r) * N + col] = f2b(v);
      }
    }
  }
}

// ------------------------------------------------- channel-attention S = (Q^T K)/8
__global__ __launch_bounds__(256)
void attn_s(const u16* __restrict__ qkv, float* __restrict__ Sp) {
  int kc = blockIdx.x, bh = blockIdx.y;
  int b = bh >> 2, h = bh & 3;
  int t = threadIdx.x, lane = t & 63, w = t >> 6;
  int fr = lane & 15, fkg = (lane >> 4) << 3;
  const u16* base = qkv + (size_t)b * 4096 * 768;
  int d0 = w << 4;
  f32x4 acc[4];
#pragma unroll
  for (int i = 0; i < 4; ++i) acc[i] = (f32x4){0.f, 0.f, 0.f, 0.f};
  int nbase = kc * 512;
  for (int ks = 0; ks < 16; ++ks) {
    int n = nbase + ks * 32 + fkg;
    const u16* qp = base + (size_t)n * 768 + h * 64;
    const u16* kp = qp + 256;
    bf16x8 aq;
#pragma unroll
    for (int j = 0; j < 8; ++j) aq[j] = (short)qp[(size_t)j * 768 + d0 + fr];
#pragma unroll
    for (int ni = 0; ni < 4; ++ni) {
      bf16x8 bk;
#pragma unroll
      for (int j = 0; j < 8; ++j) bk[j] = (short)kp[(size_t)j * 768 + ni * 16 + fr];
      acc[ni] = __builtin_amdgcn_mfma_f32_16x16x32_bf16(aq, bk, acc[ni], 0, 0, 0);
    }
  }
  float* out = Sp + (size_t)(bh * 8 + kc) * 64 * 64;
  int dr = d0 + ((lane >> 4) << 2);
#pragma unroll
  for (int ni = 0; ni < 4; ++ni)
#pragma unroll
    for (int r = 0; r < 4; ++r)
      out[(dr + r) * 64 + ni * 16 + fr] = acc[ni][r] * 0.125f;
}

// ------------------------------------------------- softmax over e (rows d), 64x64
__global__ __launch_bounds__(256)
void attn_softmax(const float* __restrict__ Sp, u16* __restrict__ attn) {
  int bh = blockIdx.x;
  int t = threadIdx.x;
  int d = t >> 2, q = t & 3;
  const float* sp = Sp + (size_t)bh * 8 * 64 * 64;
  float v[16];
#pragma unroll
  for (int i = 0; i < 16; ++i) v[i] = 0.f;
  for (int kc = 0; kc < 8; ++kc) {
    const float* p = sp + kc * 4096 + d * 64 + q * 16;
#pragma unroll
    for (int i = 0; i < 16; i += 4) {
      float4 f = *(const float4*)(p + i);
      v[i] += f.x; v[i + 1] += f.y; v[i + 2] += f.z; v[i + 3] += f.w;
    }
  }
  float m = v[0];
#pragma unroll
  for (int i = 1; i < 16; ++i) m = fmaxf(m, v[i]);
  m = fmaxf(m, __shfl_xor(m, 1));
  m = fmaxf(m, __shfl_xor(m, 2));
  float s = 0.f;
#pragma unroll
  for (int i = 0; i < 16; ++i) { v[i] = expf(v[i] - m); s += v[i]; }
  s += __shfl_xor(s, 1);
  s += __shfl_xor(s, 2);
  float inv = 1.f / s;
  u16* out = attn + (size_t)bh * 4096 + d * 64 + q * 16;
#pragma unroll
  for (int i = 0; i < 16; i += 4) {
    ushort4 u;
    u.x = f2b(v[i] * inv); u.y = f2b(v[i + 1] * inv);
    u.z = f2b(v[i + 2] * inv); u.w = f2b(v[i + 3] * inv);
    *(ushort4*)(out + i) = u;
  }
}

// ------------------------------------------------- AttOut[n,d] = sum_e V[n,e] attn[d,e]
__global__ __launch_bounds__(256)
void attn_av(const u16* __restrict__ qkv, const u16* __restrict__ attn,
             u16* __restrict__ attnout) {
  int nt = blockIdx.x, bh = blockIdx.y;
  int b = bh >> 2, h = bh & 3;
  int t = threadIdx.x, lane = t & 63, w = t >> 6;
  int fr = lane & 15, fk = (lane >> 4) << 3;
  int n0 = nt * 128 + w * 32;
  const u16* vg = qkv + (size_t)b * 4096 * 768 + 512 + h * 64;
  const u16* at = attn + (size_t)bh * 4096;
  f32x4 acc[2][4];
#pragma unroll
  for (int i = 0; i < 2; ++i)
#pragma unroll
    for (int j = 0; j < 4; ++j) acc[i][j] = (f32x4){0.f, 0.f, 0.f, 0.f};
#pragma unroll
  for (int kk = 0; kk < 2; ++kk) {
    bf16x8 av[2], bv[4];
#pragma unroll
    for (int mi = 0; mi < 2; ++mi)
      av[mi] = *(const bf16x8*)(vg + (size_t)(n0 + mi * 16 + fr) * 768 + kk * 32 + fk);
#pragma unroll
    for (int ni = 0; ni < 4; ++ni)
      bv[ni] = *(const bf16x8*)(at + (size_t)(ni * 16 + fr) * 64 + kk * 32 + fk);
#pragma unroll
    for (int mi = 0; mi < 2; ++mi)
#pragma unroll
      for (int ni = 0; ni < 4; ++ni)
        acc[mi][ni] = __builtin_amdgcn_mfma_f32_16x16x32_bf16(
            av[mi], bv[ni], acc[mi][ni], 0, 0, 0);
  }
  u16* outp = attnout + (size_t)b * 4096 * 256 + h * 64;
  int rbase = (lane >> 4) << 2;
#pragma unroll
  for (int mi = 0; mi < 2; ++mi)
#pragma unroll
    for (int ni = 0; ni < 4; ++ni)
#pragma unroll
      for (int r = 0; r < 4; ++r)
        outp[(size_t)(n0 + mi * 16 + rbase + r) * 256 + ni * 16 + fr] =
            f2b(acc[mi][ni][r]);
}

// ------------------------------------------------- row LayerNorm (256 cols), in-place
__global__ __launch_bounds__(256)
void ln2_rows(u16* __restrict__ io, const float* __restrict__ g,
              const float* __restrict__ be) {
  int w = threadIdx.x >> 6, lane = threadIdx.x & 63;
  size_t row = (size_t)blockIdx.x * 4 + w;
  u16* p = io + row * 256 + lane * 4;
  ushort4 u = *(ushort4*)p;
  float v0 = b2f(u.x), v1 = b2f(u.y), v2 = b2f(u.z), v3 = b2f(u.w);
  float s = v0 + v1 + v2 + v3;
  float ss = v0 * v0 + v1 * v1 + v2 * v2 + v3 * v3;
#pragma unroll
  for (int off = 1; off < 64; off <<= 1) {
    s += __shfl_xor(s, off);
    ss += __shfl_xor(ss, off);
  }
  float m = s * 0.00390625f;
  float var = ss * 0.00390625f - m * m;
  float r = rsqrtf(var + 1e-5f);
  int c = lane * 4;
  u.x = f2b((v0 - m) * r * g[c] + be[c]);
  u.y = f2b((v1 - m) * r * g[c + 1] + be[c + 1]);
  u.z = f2b((v2 - m) * r * g[c + 2] + be[c + 2]);
  u.w = f2b((v3 - m) * r * g[c + 3] + be[c + 3]);
  *(ushort4*)p = u;
}

// ------------------------------------------------- transpose back + residual
__global__ __launch_bounds__(256)
void resid_transpose(const u16* __restrict__ f2o, const float* __restrict__ x,
                     float* __restrict__ out) {
  int blk = blockIdx.x;
  int b = blk >> 8;
  int ct = (blk >> 6) & 3, ntl = blk & 63;
  int c0 = ct << 6, n0 = ntl << 6;
  int t = threadIdx.x;
  __shared__ float ldsT[64][65];
  {
    int n = t >> 2, cq = (t & 3) << 4;
    const u16* src = f2o + (size_t)(b * 4096 + n0 + n) * 256 + c0 + cq;
    union { uint4 v[2]; u16 s[16]; } tmp;
    tmp.v[0] = *(const uint4*)src;
    tmp.v[1] = *(const uint4*)(src + 8);
#pragma unroll
    for (int i = 0; i < 16; ++i) ldsT[cq + i][n] = b2f(tmp.s[i]);
  }
  __syncthreads();
  const float* xb = x + (size_t)b * 256 * 4096;
  float* ob = out + (size_t)b * 256 * 4096;
  int l = t & 63;
#pragma unroll
  for (int i = 0; i < 16; ++i) {
    int c = i * 4 + (t >> 6);
    size_t idx = (size_t)(c0 + c) * 4096 + n0 + l;
    ob[idx] = ldsT[c][l] + xb[idx];
  }
}

// =================================================================== launch
extern "C" void kernel_launch(void* const* d_in, const int* in_sizes, int n_in,
                              void* d_out, int out_size, void* d_ws, size_t ws_size,
                              hipStream_t stream) {
  (void)in_sizes; (void)n_in; (void)out_size;
  const float* x      = (const float*)d_in[0];
  const float* w_qkv  = (const float*)d_in[1];
  const float* b_qkv  = (const float*)d_in[2];
  const float* w_proj = (const float*)d_in[3];
  const float* b_proj = (const float*)d_in[4];
  const float* w_ffn1 = (const float*)d_in[5];
  const float* b_ffn1 = (const float*)d_in[6];
  const float* w_ffn2 = (const float*)d_in[7];
  const float* b_ffn2 = (const float*)d_in[8];
  const float* g1  = (const float*)d_in[9];
  const float* be1 = (const float*)d_in[10];
  const float* g2  = (const float*)d_in[11];
  const float* be2 = (const float*)d_in[12];

  u16* p = (u16*)d_ws;
  u16* wq = p;       p += 196608;               // w_qkv bf16 (768x256)
  u16* wp = p;       p += 65536;                // w_proj bf16 (256x256)
  u16* w1 = p;       p += 524288;               // w_ffn1 bf16 (2048x256)
  u16* w2 = p;       p += 524288;               // w_ffn2 bf16 (256x2048)
  u16* xln = p;      p += (size_t)32768 * 256;  // LN1 output (B*N, C)
  u16* qkv = p;      p += (size_t)32768 * 768;  // QKV (B*N, 3C)
  u16* attnw = p;    p += 32 * 64 * 64;         // attention probs (bh,64,64)
  u16* attnout = p;  p += (size_t)32768 * 256;  // PV output (B*N, C)
  u16* projout = p;  p += (size_t)32768 * 256;  // proj out / LN2 in-place
  u16* ffn2 = p;     p += (size_t)32768 * 256;  // FFN2 out (B*N, C)
  float* Sp = (float*)p; p += (size_t)2 * 32 * 8 * 64 * 64;  // S partials f32
  u16* ffn1 = p;                                // FFN1 buffer (variable size)

  size_t fixed = (size_t)(p - (u16*)d_ws);
  // pick fewest FFN M-chunks that fit the workspace
  int nc = 4;
  if (ws_size >= (fixed + (size_t)32768 * 2048) * 2) nc = 1;
  else if (ws_size >= (fixed + (size_t)16384 * 2048) * 2) nc = 2;
  int Mc = 32768 / nc;

  cvt_bf16<<<192, 256, 0, stream>>>(w_qkv, wq, 196608);
  cvt_bf16<<<64, 256, 0, stream>>>(w_proj, wp, 65536);
  cvt_bf16<<<512, 256, 0, stream>>>(w_ffn1, w1, 524288);
  cvt_bf16<<<512, 256, 0, stream>>>(w_ffn2, w2, 524288);

  ln1_transpose<<<512, 256, 0, stream>>>(x, g1, be1, xln);

  gemm_bt<<<dim3(6, 256), 256, 0, stream>>>(xln, wq, b_qkv, qkv, 768, 256, 0);

  attn_s<<<dim3(8, 32), 256, 0, stream>>>(qkv, Sp);
  attn_softmax<<<32, 256, 0, stream>>>(Sp, attnw);
  attn_av<<<dim3(32, 32), 256, 0, stream>>>(qkv, attnw, attnout);

  gemm_bt<<<dim3(2, 256), 256, 0, stream>>>(attnout, wp, b_proj, projout, 256, 256, 0);
  ln2_rows<<<8192, 256, 0, stream>>>(projout, g2, be2);

  for (int mc = 0; mc < nc; ++mc) {
    gemm_bt<<<dim3(16, Mc / 128), 256, 0, stream>>>(
        projout + (size_t)mc * Mc * 256, w1, b_ffn1, ffn1, 2048, 256, 1);
    gemm_bt<<<dim3(2, Mc / 128), 256, 0, stream>>>(
        ffn1, w2, b_ffn2, ffn2 + (size_t)mc * Mc * 256, 256, 2048, 0);
  }

  resid_transpose<<<2048, 256, 0, stream>>>(ffn2, x, (float*)d_out);
}